// Round 11
// baseline (54.371 us; speedup 1.0000x reference)
//
#include <hip/hip_runtime.h>

typedef __bf16 bf16_t;
typedef bf16_t bf16x8 __attribute__((ext_vector_type(8)));
typedef float f32x4 __attribute__((ext_vector_type(4)));

#define Bsz 4096   // batch rows (M)
#define Csz 4096   // centers (N)
#define Dsz 1024   // data dim (K)
#define BM 128
#define BN 128
#define BK 64
#define NT (Dsz/BK)         // 16 K-tiles

// RNE f32 -> bf16 bits
__device__ inline unsigned short f2bf(float f){
  unsigned u = __float_as_uint(f);
  u += 0x7FFFu + ((u >> 16) & 1u);
  return (unsigned short)(u >> 16);
}

// ---------------- prep: x2/c2 (f32 exact) + bf16 convert + out=bias --------
// 1024 blocks x 4 waves x 2 rows = 8192 rows. Also initializes out[row]=bias
// so the GEMM can finish with device-scope atomicAdd (stream order guarantees
// prep completes before the GEMM kernel starts).
__global__ __launch_bounds__(256) void prep_kernel(
    const float* __restrict__ x, const float* __restrict__ cen,
    const float* __restrict__ bias,
    unsigned short* __restrict__ xb, unsigned short* __restrict__ cb,
    float* __restrict__ x2, float* __restrict__ c2,
    float* __restrict__ out)
{
  const int wid  = threadIdx.x >> 6;
  const int lane = threadIdx.x & 63;
  #pragma unroll
  for (int rr = 0; rr < 2; ++rr){
    const int w = blockIdx.x * 8 + wid * 2 + rr;   // 0..8191
    const float* src; unsigned short* dst; float* sq; int row;
    if (w < Bsz) { row = w;       src = x;   dst = xb; sq = x2; }
    else         { row = w - Bsz; src = cen; dst = cb; sq = c2; }

    const float4* s4 = (const float4*)(src + (size_t)row * Dsz);
    unsigned short* d = dst + (size_t)row * Dsz;
    float ss = 0.f;
    #pragma unroll
    for (int t = 0; t < 4; ++t){
      float4 v = s4[t * 64 + lane];
      ss += v.x*v.x + v.y*v.y + v.z*v.z + v.w*v.w;
      ushort4 u; u.x = f2bf(v.x); u.y = f2bf(v.y); u.z = f2bf(v.z); u.w = f2bf(v.w);
      *(ushort4*)(d + (size_t)(t * 64 + lane) * 4) = u;
    }
    #pragma unroll
    for (int off = 32; off >= 1; off >>= 1) ss += __shfl_xor(ss, off, 64);
    if (lane == 0){
      sq[row] = ss;
      if (w < Bsz) out[row] = bias[0];   // re-init every call (atomic target)
    }
  }
}

// --------- R8-proven 128x128 GEMM + fused RBF epilogue, atomic finish ------
// 256 thr = 4 waves (2 wr x 2 wc). Per wave: 64x64 output = 4x4 frags 16x16.
// Single LDS buffer (A 128x64 + B 128x64 bf16 = 32 KiB) -> 4 blocks/CU.
// Per tile: stage via 8x global_load_lds(16B) -> __syncthreads() -> kk=0,1
// plain C++ bf16x8 reads + 16 MFMA (compiler-scheduled lgkmcnt) ->
// __syncthreads(). Swizzle: LDS[r][c16] = G[r][c16 ^ (r&7)] -> 0 conflicts.
// R11 FIX: co-resident blocks on one CU are ids {i, i+256, i+512, i+768}
// (round-robin dispatch). R8's koff=(id&3)*4 gave them IDENTICAL phases
// (256 % 4 == 0) -- stagger never de-phased the CU. New koff uses (id>>8)
// for intra-CU separation (4 tiles apart) + (id&3) for cross-CU jitter.
// Epilogue: d2 -> dist -> exp -> *W -> 16-lane reduce -> atomicAdd(out[row]).
__global__ __launch_bounds__(256, 4) void rbf_gemm_kernel(
    const unsigned short* __restrict__ xb, const unsigned short* __restrict__ cb,
    const float* __restrict__ x2, const float* __restrict__ c2,
    const float* __restrict__ beta, const float* __restrict__ W,
    float* __restrict__ out)
{
  __shared__ __align__(16) unsigned short As[BM * BK];  // 16 KiB
  __shared__ __align__(16) unsigned short Bs[BN * BK];  // 16 KiB

  const int tid  = threadIdx.x;
  const int wid  = tid >> 6;
  const int lane = tid & 63;
  const int wr   = wid >> 1;        // 0..1
  const int wc   = wid & 1;         // 0..1
  const int l15  = lane & 15;
  const int lhi  = lane >> 4;

  // XCD mapping: xcd = id%8; each XCD owns two 8x8 (bm,bn) rects -> ~4 MB
  // L2 working set per XCD. (R4: FETCH 37.5 -> 26 MB)
  const int id   = blockIdx.x;          // 0..1023
  const int xcd  = id & 7;
  const int jj   = id >> 3;             // 0..127
  const int rect = xcd + 8 * (jj >> 6); // 0..15
  const int pos  = jj & 63;             // 0..63
  const int bm   = (rect & 3) * 8 + (pos & 7);
  const int bn   = (rect >> 2) * 8 + (pos >> 3);

  const unsigned short* gA = xb + (size_t)(bm * BM) * Dsz;
  const unsigned short* gB = cb + (size_t)(bn * BN) * Dsz;

  // staging: one gload_lds = 64 lanes x 16B = 8 rows x 8 chunks; 256 thr
  // cover 32 rows/pass; 4 passes per 128-row panel; 8 gload/thread/tile.
  const int srow   = tid >> 3;                 // 0..31
  const int schunk = (tid & 7) ^ (srow & 7);   // pre-swizzled source chunk

  // K-loop stagger: intra-CU phase from (id>>8) (co-resident blocks differ
  // by 256), cross-CU jitter from (id&3). koff in [0,16).
  const int koff = (((id >> 8) & 3) << 2) | (id & 3);

  f32x4 acc[4][4];
  #pragma unroll
  for (int mi = 0; mi < 4; ++mi)
    #pragma unroll
    for (int ni = 0; ni < 4; ++ni)
      acc[mi][ni] = (f32x4){0.f, 0.f, 0.f, 0.f};

  for (int t = 0; t < NT; ++t){
    const int tp = (t + koff) & (NT - 1);      // physical K-tile index
    // ---- stage tile tp (linear LDS dest, pre-swizzled global source) ----
    #pragma unroll
    for (int r_ = 0; r_ < 4; ++r_){
      const unsigned short* ga_ = gA + (size_t)(r_*32 + srow) * Dsz + tp*BK + schunk*8;
      __builtin_amdgcn_global_load_lds(
        (const __attribute__((address_space(1))) unsigned int*)ga_,
        (__attribute__((address_space(3))) unsigned int*)&As[r_*2048 + wid*512], 16, 0, 0);
      const unsigned short* gb_ = gB + (size_t)(r_*32 + srow) * Dsz + tp*BK + schunk*8;
      __builtin_amdgcn_global_load_lds(
        (const __attribute__((address_space(1))) unsigned int*)gb_,
        (__attribute__((address_space(3))) unsigned int*)&Bs[r_*2048 + wid*512], 16, 0, 0);
    }
    __syncthreads();   // compiler drains vmcnt before barrier -> tile ready

    // ---- compute: plain C++ reads, compiler-scheduled waits ----
    #pragma unroll
    for (int kk = 0; kk < 2; ++kk){
      bf16x8 av[4], bv[4];
      const int chunk = ((kk*4 + lhi) ^ (l15 & 7)) * 8;
      #pragma unroll
      for (int mi = 0; mi < 4; ++mi)
        av[mi] = *(const bf16x8*)&As[(wr*64 + mi*16 + l15)*64 + chunk];
      #pragma unroll
      for (int ni = 0; ni < 4; ++ni)
        bv[ni] = *(const bf16x8*)&Bs[(wc*64 + ni*16 + l15)*64 + chunk];
      #pragma unroll
      for (int mi = 0; mi < 4; ++mi)
        #pragma unroll
        for (int ni = 0; ni < 4; ++ni)
          acc[mi][ni] = __builtin_amdgcn_mfma_f32_16x16x32_bf16(av[mi], bv[ni], acc[mi][ni], 0, 0, 0);
    }
    __syncthreads();   // protect LDS before next stage overwrites
  }

  // ---- fused epilogue: d2 -> dist -> exp -> *W, column-sum, atomic out ----
  const int rowbase0 = bm * BM + wr * 64;
  f32x4 rs[4];
  #pragma unroll
  for (int mi = 0; mi < 4; ++mi) rs[mi] = (f32x4){0.f, 0.f, 0.f, 0.f};

  f32x4 x2r[4];
  #pragma unroll
  for (int mi = 0; mi < 4; ++mi)
    x2r[mi] = *(const f32x4*)&x2[rowbase0 + mi * 16 + lhi * 4];

  #pragma unroll
  for (int ni = 0; ni < 4; ++ni){
    const int col = bn * BN + wc * 64 + ni * 16 + l15;
    const float c2v = c2[col], bt = beta[col], wv = W[col];
    #pragma unroll
    for (int mi = 0; mi < 4; ++mi)
      #pragma unroll
      for (int j = 0; j < 4; ++j){
        float s    = acc[mi][ni][j];
        float d2   = x2r[mi][j] + c2v - 2.0f * s;
        float dist = sqrtf(fmaxf(d2, 0.0f));
        rs[mi][j] += wv * __expf(-bt * dist);   // exp(<=0) can't be inf
      }
  }

  // reduce over the 16 lanes holding different cols; one atomicAdd per row
  #pragma unroll
  for (int mi = 0; mi < 4; ++mi){
    #pragma unroll
    for (int j = 0; j < 4; ++j){
      float v = rs[mi][j];
      v += __shfl_xor(v, 1, 16);
      v += __shfl_xor(v, 2, 16);
      v += __shfl_xor(v, 4, 16);
      v += __shfl_xor(v, 8, 16);
      if (l15 == 0)
        atomicAdd(&out[rowbase0 + mi * 16 + lhi * 4 + j], v);
    }
  }
}

// ---------------- naive f32 fallback (only if ws too small) ----------------
__global__ __launch_bounds__(256) void rbf_naive_kernel(
    const float* __restrict__ x, const float* __restrict__ cen,
    const float* __restrict__ beta, const float* __restrict__ W,
    const float* __restrict__ bias, float* __restrict__ out)
{
  __shared__ float4 xs4[Dsz / 4];
  __shared__ float red[256];
  int b = blockIdx.x;
  for (int i = threadIdx.x; i < Dsz / 4; i += 256)
    xs4[i] = ((const float4*)(x + (size_t)b * Dsz))[i];
  __syncthreads();
  float acc = 0.f;
  for (int j = threadIdx.x; j < Csz; j += 256){
    const float4* c4 = (const float4*)(cen + (size_t)j * Dsz);
    float d2 = 0.f;
    for (int k = 0; k < Dsz / 4; ++k){
      float4 cv = c4[k], xv = xs4[k];
      float a0 = xv.x - cv.x, a1 = xv.y - cv.y, a2 = xv.z - cv.z, a3 = xv.w - cv.w;
      d2 += a0*a0 + a1*a1 + a2*a2 + a3*a3;
    }
    acc += W[j] * expf(-beta[j] * sqrtf(fmaxf(d2, 0.f)));
  }
  red[threadIdx.x] = acc;
  __syncthreads();
  for (int s = 128; s >= 1; s >>= 1){
    if (threadIdx.x < s) red[threadIdx.x] += red[threadIdx.x + s];
    __syncthreads();
  }
  if (threadIdx.x == 0) out[b] = red[0] + bias[0];
}

extern "C" void kernel_launch(void* const* d_in, const int* in_sizes, int n_in,
                              void* d_out, int out_size, void* d_ws, size_t ws_size,
                              hipStream_t stream)
{
  const float* x    = (const float*)d_in[0];
  const float* cen  = (const float*)d_in[1];
  const float* beta = (const float*)d_in[2];
  const float* W    = (const float*)d_in[3];
  const float* bias = (const float*)d_in[4];
  float* out = (float*)d_out;

  const size_t off_xb = 0;
  const size_t off_cb = off_xb + (size_t)Bsz * Dsz * sizeof(unsigned short);
  const size_t off_x2 = off_cb + (size_t)Csz * Dsz * sizeof(unsigned short);
  const size_t off_c2 = off_x2 + (size_t)Bsz * sizeof(float);
  const size_t need   = off_c2 + (size_t)Csz * sizeof(float);

  if (ws_size < need){
    rbf_naive_kernel<<<Bsz, 256, 0, stream>>>(x, cen, beta, W, bias, out);
    return;
  }

  char* ws = (char*)d_ws;
  unsigned short* xb = (unsigned short*)(ws + off_xb);
  unsigned short* cb = (unsigned short*)(ws + off_cb);
  float* x2 = (float*)(ws + off_x2);
  float* c2 = (float*)(ws + off_c2);

  prep_kernel<<<1024, 256, 0, stream>>>(x, cen, bias, xb, cb, x2, c2, out);
  rbf_gemm_kernel<<<1024, 256, 0, stream>>>(xb, cb, x2, c2, beta, W, out);
}

// Round 12
// 53.768 us; speedup vs baseline: 1.0112x; 1.0112x over previous
//
#include <hip/hip_runtime.h>

typedef __bf16 bf16_t;
typedef bf16_t bf16x8 __attribute__((ext_vector_type(8)));
typedef float f32x4 __attribute__((ext_vector_type(4)));

#define Bsz 4096   // batch rows (M)
#define Csz 4096   // centers (N)
#define Dsz 1024   // data dim (K)
#define BM 128
#define BN 128
#define BK 64
#define NT (Dsz/BK)         // 16 K-tiles

// RNE f32 -> bf16 bits
__device__ inline unsigned short f2bf(float f){
  unsigned u = __float_as_uint(f);
  u += 0x7FFFu + ((u >> 16) & 1u);
  return (unsigned short)(u >> 16);
}

// ---------------- prep: x2/c2 (f32 exact) + bf16 convert + out=bias --------
// 1024 blocks x 4 waves x 2 rows = 8192 rows. Also initializes out[row]=bias
// so the GEMM can finish with device-scope atomicAdd (stream order guarantees
// prep completes before the GEMM kernel starts). ~HBM-bound (48 MB traffic).
__global__ __launch_bounds__(256) void prep_kernel(
    const float* __restrict__ x, const float* __restrict__ cen,
    const float* __restrict__ bias,
    unsigned short* __restrict__ xb, unsigned short* __restrict__ cb,
    float* __restrict__ x2, float* __restrict__ c2,
    float* __restrict__ out)
{
  const int wid  = threadIdx.x >> 6;
  const int lane = threadIdx.x & 63;
  #pragma unroll
  for (int rr = 0; rr < 2; ++rr){
    const int w = blockIdx.x * 8 + wid * 2 + rr;   // 0..8191
    const float* src; unsigned short* dst; float* sq; int row;
    if (w < Bsz) { row = w;       src = x;   dst = xb; sq = x2; }
    else         { row = w - Bsz; src = cen; dst = cb; sq = c2; }

    const float4* s4 = (const float4*)(src + (size_t)row * Dsz);
    unsigned short* d = dst + (size_t)row * Dsz;
    float ss = 0.f;
    #pragma unroll
    for (int t = 0; t < 4; ++t){
      float4 v = s4[t * 64 + lane];
      ss += v.x*v.x + v.y*v.y + v.z*v.z + v.w*v.w;
      ushort4 u; u.x = f2bf(v.x); u.y = f2bf(v.y); u.z = f2bf(v.z); u.w = f2bf(v.w);
      *(ushort4*)(d + (size_t)(t * 64 + lane) * 4) = u;
    }
    #pragma unroll
    for (int off = 32; off >= 1; off >>= 1) ss += __shfl_xor(ss, off, 64);
    if (lane == 0){
      sq[row] = ss;
      if (w < Bsz) out[row] = bias[0];   // re-init every call (atomic target)
    }
  }
}

// --------- R10-proven 128x128 GEMM + fused RBF epilogue, atomic finish -----
// 256 thr = 4 waves (2 wr x 2 wc). Per wave: 64x64 output = 4x4 frags 16x16.
// Single LDS buffer (A 128x64 + B 128x64 bf16 = 32 KiB) -> 4 blocks/CU.
// Per tile: stage via 8x global_load_lds(16B) -> __syncthreads() -> kk=0,1
// plain C++ bf16x8 reads + 16 MFMA (compiler-scheduled lgkmcnt) ->
// __syncthreads(). Swizzle: LDS[r][c16] = G[r][c16 ^ (r&7)] -> 0 conflicts.
// koff = (id&3)*4: R10 form (best FETCH 24.9 MB; R11's intra-CU variant was
// null on time and raised FETCH -> reverted).
// Epilogue: d2 -> dist -> exp -> *W -> 16-lane shfl reduce -> cross-wc LDS
// combine (reuses As after final barrier) -> ONE atomicAdd per (row,wr):
// 256 atomics/block (halved vs R10).
__global__ __launch_bounds__(256, 4) void rbf_gemm_kernel(
    const unsigned short* __restrict__ xb, const unsigned short* __restrict__ cb,
    const float* __restrict__ x2, const float* __restrict__ c2,
    const float* __restrict__ beta, const float* __restrict__ W,
    float* __restrict__ out)
{
  __shared__ __align__(16) unsigned short As[BM * BK];  // 16 KiB
  __shared__ __align__(16) unsigned short Bs[BN * BK];  // 16 KiB

  const int tid  = threadIdx.x;
  const int wid  = tid >> 6;
  const int lane = tid & 63;
  const int wr   = wid >> 1;        // 0..1
  const int wc   = wid & 1;         // 0..1
  const int l15  = lane & 15;
  const int lhi  = lane >> 4;

  // XCD mapping: xcd = id%8; each XCD owns two 8x8 (bm,bn) rects -> ~4 MB
  // L2 working set per XCD. (R4: FETCH 37.5 -> 26 MB)
  const int id   = blockIdx.x;          // 0..1023
  const int xcd  = id & 7;
  const int jj   = id >> 3;             // 0..127
  const int rect = xcd + 8 * (jj >> 6); // 0..15
  const int pos  = jj & 63;             // 0..63
  const int bm   = (rect & 3) * 8 + (pos & 7);
  const int bn   = (rect >> 2) * 8 + (pos >> 3);

  const unsigned short* gA = xb + (size_t)(bm * BM) * Dsz;
  const unsigned short* gB = cb + (size_t)(bn * BN) * Dsz;

  // staging: one gload_lds = 64 lanes x 16B = 8 rows x 8 chunks; 256 thr
  // cover 32 rows/pass; 4 passes per 128-row panel; 8 gload/thread/tile.
  const int srow   = tid >> 3;                 // 0..31
  const int schunk = (tid & 7) ^ (srow & 7);   // pre-swizzled source chunk

  // K-loop stagger, R10 form (cross-CU HBM de-bursting; best measured FETCH)
  const int koff = (id & 3) << 2;              // 0,4,8,12

  f32x4 acc[4][4];
  #pragma unroll
  for (int mi = 0; mi < 4; ++mi)
    #pragma unroll
    for (int ni = 0; ni < 4; ++ni)
      acc[mi][ni] = (f32x4){0.f, 0.f, 0.f, 0.f};

  for (int t = 0; t < NT; ++t){
    const int tp = (t + koff) & (NT - 1);      // physical K-tile index
    // ---- stage tile tp (linear LDS dest, pre-swizzled global source) ----
    #pragma unroll
    for (int r_ = 0; r_ < 4; ++r_){
      const unsigned short* ga_ = gA + (size_t)(r_*32 + srow) * Dsz + tp*BK + schunk*8;
      __builtin_amdgcn_global_load_lds(
        (const __attribute__((address_space(1))) unsigned int*)ga_,
        (__attribute__((address_space(3))) unsigned int*)&As[r_*2048 + wid*512], 16, 0, 0);
      const unsigned short* gb_ = gB + (size_t)(r_*32 + srow) * Dsz + tp*BK + schunk*8;
      __builtin_amdgcn_global_load_lds(
        (const __attribute__((address_space(1))) unsigned int*)gb_,
        (__attribute__((address_space(3))) unsigned int*)&Bs[r_*2048 + wid*512], 16, 0, 0);
    }
    __syncthreads();   // compiler drains vmcnt before barrier -> tile ready

    // ---- compute: plain C++ reads, compiler-scheduled waits ----
    #pragma unroll
    for (int kk = 0; kk < 2; ++kk){
      bf16x8 av[4], bv[4];
      const int chunk = ((kk*4 + lhi) ^ (l15 & 7)) * 8;
      #pragma unroll
      for (int mi = 0; mi < 4; ++mi)
        av[mi] = *(const bf16x8*)&As[(wr*64 + mi*16 + l15)*64 + chunk];
      #pragma unroll
      for (int ni = 0; ni < 4; ++ni)
        bv[ni] = *(const bf16x8*)&Bs[(wc*64 + ni*16 + l15)*64 + chunk];
      #pragma unroll
      for (int mi = 0; mi < 4; ++mi)
        #pragma unroll
        for (int ni = 0; ni < 4; ++ni)
          acc[mi][ni] = __builtin_amdgcn_mfma_f32_16x16x32_bf16(av[mi], bv[ni], acc[mi][ni], 0, 0, 0);
    }
    __syncthreads();   // protect LDS before next stage overwrites
  }

  // ---- fused epilogue: d2 -> dist -> exp -> *W, column-sum ----
  const int rowbase0 = bm * BM + wr * 64;
  f32x4 rs[4];
  #pragma unroll
  for (int mi = 0; mi < 4; ++mi) rs[mi] = (f32x4){0.f, 0.f, 0.f, 0.f};

  f32x4 x2r[4];
  #pragma unroll
  for (int mi = 0; mi < 4; ++mi)
    x2r[mi] = *(const f32x4*)&x2[rowbase0 + mi * 16 + lhi * 4];

  #pragma unroll
  for (int ni = 0; ni < 4; ++ni){
    const int col = bn * BN + wc * 64 + ni * 16 + l15;
    const float c2v = c2[col], bt = beta[col], wv = W[col];
    #pragma unroll
    for (int mi = 0; mi < 4; ++mi)
      #pragma unroll
      for (int j = 0; j < 4; ++j){
        float s    = acc[mi][ni][j];
        float d2   = x2r[mi][j] + c2v - 2.0f * s;
        float dist = sqrtf(fmaxf(d2, 0.0f));
        rs[mi][j] += wv * __expf(-bt * dist);   // exp(<=0) can't be inf
      }
  }

  // 16-lane shfl reduce (cols within a frag row)
  #pragma unroll
  for (int mi = 0; mi < 4; ++mi)
    #pragma unroll
    for (int j = 0; j < 4; ++j){
      float v = rs[mi][j];
      v += __shfl_xor(v, 1, 16);
      v += __shfl_xor(v, 2, 16);
      v += __shfl_xor(v, 4, 16);
      v += __shfl_xor(v, 8, 16);
      rs[mi][j] = v;
    }

  // cross-wc combine through LDS (As is dead after the last barrier above):
  // wc=1 waves deposit, wc=0 waves add -> one atomicAdd per (row, wr).
  float* red = (float*)As;          // [2 wr][64 rows]
  if (wc == 1 && l15 == 0){
    #pragma unroll
    for (int mi = 0; mi < 4; ++mi)
      #pragma unroll
      for (int j = 0; j < 4; ++j)
        red[wr * 64 + mi * 16 + lhi * 4 + j] = rs[mi][j];
  }
  __syncthreads();
  if (wc == 0 && l15 == 0){
    #pragma unroll
    for (int mi = 0; mi < 4; ++mi)
      #pragma unroll
      for (int j = 0; j < 4; ++j){
        const int r = mi * 16 + lhi * 4 + j;
        atomicAdd(&out[rowbase0 + r], rs[mi][j] + red[wr * 64 + r]);
      }
  }
}

// ---------------- naive f32 fallback (only if ws too small) ----------------
__global__ __launch_bounds__(256) void rbf_naive_kernel(
    const float* __restrict__ x, const float* __restrict__ cen,
    const float* __restrict__ beta, const float* __restrict__ W,
    const float* __restrict__ bias, float* __restrict__ out)
{
  __shared__ float4 xs4[Dsz / 4];
  __shared__ float red[256];
  int b = blockIdx.x;
  for (int i = threadIdx.x; i < Dsz / 4; i += 256)
    xs4[i] = ((const float4*)(x + (size_t)b * Dsz))[i];
  __syncthreads();
  float acc = 0.f;
  for (int j = threadIdx.x; j < Csz; j += 256){
    const float4* c4 = (const float4*)(cen + (size_t)j * Dsz);
    float d2 = 0.f;
    for (int k = 0; k < Dsz / 4; ++k){
      float4 cv = c4[k], xv = xs4[k];
      float a0 = xv.x - cv.x, a1 = xv.y - cv.y, a2 = xv.z - cv.z, a3 = xv.w - cv.w;
      d2 += a0*a0 + a1*a1 + a2*a2 + a3*a3;
    }
    acc += W[j] * expf(-beta[j] * sqrtf(fmaxf(d2, 0.f)));
  }
  red[threadIdx.x] = acc;
  __syncthreads();
  for (int s = 128; s >= 1; s >>= 1){
    if (threadIdx.x < s) red[threadIdx.x] += red[threadIdx.x + s];
    __syncthreads();
  }
  if (threadIdx.x == 0) out[b] = red[0] + bias[0];
}

extern "C" void kernel_launch(void* const* d_in, const int* in_sizes, int n_in,
                              void* d_out, int out_size, void* d_ws, size_t ws_size,
                              hipStream_t stream)
{
  const float* x    = (const float*)d_in[0];
  const float* cen  = (const float*)d_in[1];
  const float* beta = (const float*)d_in[2];
  const float* W    = (const float*)d_in[3];
  const float* bias = (const float*)d_in[4];
  float* out = (float*)d_out;

  const size_t off_xb = 0;
  const size_t off_cb = off_xb + (size_t)Bsz * Dsz * sizeof(unsigned short);
  const size_t off_x2 = off_cb + (size_t)Csz * Dsz * sizeof(unsigned short);
  const size_t off_c2 = off_x2 + (size_t)Bsz * sizeof(float);
  const size_t need   = off_c2 + (size_t)Csz * sizeof(float);

  if (ws_size < need){
    rbf_naive_kernel<<<Bsz, 256, 0, stream>>>(x, cen, beta, W, bias, out);
    return;
  }

  char* ws = (char*)d_ws;
  unsigned short* xb = (unsigned short*)(ws + off_xb);
  unsigned short* cb = (unsigned short*)(ws + off_cb);
  float* x2 = (float*)(ws + off_x2);
  float* c2 = (float*)(ws + off_c2);

  prep_kernel<<<1024, 256, 0, stream>>>(x, cen, bias, xb, cb, x2, c2, out);
  rbf_gemm_kernel<<<1024, 256, 0, stream>>>(xb, cb, x2, c2, beta, W, out);
}

// Round 13
// 42.374 us; speedup vs baseline: 1.2831x; 1.2689x over previous
//
#include <hip/hip_runtime.h>

typedef int i32x4 __attribute__((ext_vector_type(4)));
typedef float f32x4 __attribute__((ext_vector_type(4)));

#define Bsz 4096   // batch rows (M)
#define Csz 4096   // centers (N)
#define Dsz 1024   // data dim (K)
#define BM 128
#define BN 128
#define BK 128              // i8: 128x128 i8 tile = 16 KB per matrix
#define NT (Dsz/BK)         // 8 K-tiles

// ------------- prep: x2/c2 + per-row i8 quantization + out=bias -------------
// 1024 blocks x 4 waves x 2 rows. Single pass: the 16 row-elements/lane stay
// in registers; after the {sum,max} butterfly reduce, quantize from regs.
// q = rint(v * 127/rowmax), s = rowmax/127 -> |q| <= 127 by construction.
__global__ __launch_bounds__(256) void prep_kernel(
    const float* __restrict__ x, const float* __restrict__ cen,
    const float* __restrict__ bias,
    signed char* __restrict__ xq, signed char* __restrict__ cq,
    float* __restrict__ x2, float* __restrict__ c2,
    float* __restrict__ sx, float* __restrict__ sc,
    float* __restrict__ out)
{
  const int wid  = threadIdx.x >> 6;
  const int lane = threadIdx.x & 63;
  #pragma unroll
  for (int rr = 0; rr < 2; ++rr){
    const int w = blockIdx.x * 8 + wid * 2 + rr;   // 0..8191
    const float* src; signed char* dst; float* sq; float* sv; int row;
    if (w < Bsz) { row = w;       src = x;   dst = xq; sq = x2; sv = sx; }
    else         { row = w - Bsz; src = cen; dst = cq; sq = c2; sv = sc; }

    const float4* s4 = (const float4*)(src + (size_t)row * Dsz);
    float4 v[4];
    float ss = 0.f, mx = 0.f;
    #pragma unroll
    for (int t = 0; t < 4; ++t){
      v[t] = s4[t * 64 + lane];
      ss += v[t].x*v[t].x + v[t].y*v[t].y + v[t].z*v[t].z + v[t].w*v[t].w;
      mx = fmaxf(mx, fmaxf(fmaxf(fabsf(v[t].x), fabsf(v[t].y)),
                           fmaxf(fabsf(v[t].z), fabsf(v[t].w))));
    }
    #pragma unroll
    for (int off = 32; off >= 1; off >>= 1){
      ss += __shfl_xor(ss, off, 64);
      mx  = fmaxf(mx, __shfl_xor(mx, off, 64));
    }
    const float inv = (mx > 0.f) ? 127.0f / mx : 0.f;
    if (lane == 0){
      sq[row] = ss;
      sv[row] = mx * (1.0f / 127.0f);
      if (w < Bsz) out[row] = bias[0];   // re-init every call (atomic target)
    }
    unsigned* dq = (unsigned*)(dst + (size_t)row * Dsz);
    #pragma unroll
    for (int t = 0; t < 4; ++t){
      const int q0 = (int)rintf(v[t].x * inv);
      const int q1 = (int)rintf(v[t].y * inv);
      const int q2 = (int)rintf(v[t].z * inv);
      const int q3 = (int)rintf(v[t].w * inv);
      dq[t * 64 + lane] = (unsigned)(q0 & 0xFF) | ((unsigned)(q1 & 0xFF) << 8) |
                          ((unsigned)(q2 & 0xFF) << 16) | ((unsigned)(q3 & 0xFF) << 24);
    }
  }
}

// ------- i8 128x128 GEMM (BK=128, 8 tiles) + fused RBF epilogue -------
// Same winning skeleton as R12 (byte-geometry identical: 128 B rows, same
// XOR chunk swizzle, same staging passes, plain compiler scheduling,
// 32 KiB LDS -> 4 blocks/CU), but i8 halves: MFMA issue time (K=64/instr),
// LDS traffic, FETCH, and the tile count 16->8 (half the barrier/drain
// rounds -- the measured bottleneck). i32 dot is EXACT (<= 1.6e7 < 2^31).
// Epilogue: d2 = x2 + c2 - 2*sx*sc*dot_i32 -> dist -> exp -> *W ->
// 16-lane reduce -> cross-wc LDS combine -> one atomicAdd per (row,wr).
__global__ __launch_bounds__(256, 4) void rbf_gemm_kernel(
    const signed char* __restrict__ xq, const signed char* __restrict__ cq,
    const float* __restrict__ x2, const float* __restrict__ c2,
    const float* __restrict__ sx, const float* __restrict__ sc,
    const float* __restrict__ beta, const float* __restrict__ W,
    float* __restrict__ out)
{
  __shared__ __align__(16) signed char As[BM * BK];  // 16 KiB
  __shared__ __align__(16) signed char Bs[BN * BK];  // 16 KiB

  const int tid  = threadIdx.x;
  const int wid  = tid >> 6;
  const int lane = tid & 63;
  const int wr   = wid >> 1;        // 0..1
  const int wc   = wid & 1;         // 0..1
  const int l15  = lane & 15;
  const int lhi  = lane >> 4;

  // XCD mapping: xcd = id%8; each XCD owns two 8x8 (bm,bn) rects (R4-proven).
  const int id   = blockIdx.x;          // 0..1023
  const int xcd  = id & 7;
  const int jj   = id >> 3;             // 0..127
  const int rect = xcd + 8 * (jj >> 6); // 0..15
  const int pos  = jj & 63;             // 0..63
  const int bm   = (rect & 3) * 8 + (pos & 7);
  const int bn   = (rect >> 2) * 8 + (pos >> 3);

  const signed char* gA = xq + (size_t)(bm * BM) * Dsz;
  const signed char* gB = cq + (size_t)(bn * BN) * Dsz;

  // staging: one gload_lds = 64 lanes x 16B = 8 rows x 8 chunks (128B rows,
  // same byte geometry as the bf16 version); 4 passes per 128-row panel.
  const int srow   = tid >> 3;                 // 0..31
  const int schunk = (tid & 7) ^ (srow & 7);   // pre-swizzled source chunk

  // K-loop stagger (cross-CU HBM de-bursting), scaled to NT=8
  const int koff = (id & 3) << 1;              // 0,2,4,6

  i32x4 acc[4][4];
  #pragma unroll
  for (int mi = 0; mi < 4; ++mi)
    #pragma unroll
    for (int ni = 0; ni < 4; ++ni)
      acc[mi][ni] = (i32x4){0, 0, 0, 0};

  for (int t = 0; t < NT; ++t){
    const int tp = (t + koff) & (NT - 1);      // physical K-tile index
    // ---- stage tile tp (linear LDS dest, pre-swizzled global source) ----
    #pragma unroll
    for (int r_ = 0; r_ < 4; ++r_){
      const signed char* ga_ = gA + (size_t)(r_*32 + srow) * Dsz + tp*BK + schunk*16;
      __builtin_amdgcn_global_load_lds(
        (const __attribute__((address_space(1))) unsigned int*)ga_,
        (__attribute__((address_space(3))) unsigned int*)&As[r_*4096 + wid*1024], 16, 0, 0);
      const signed char* gb_ = gB + (size_t)(r_*32 + srow) * Dsz + tp*BK + schunk*16;
      __builtin_amdgcn_global_load_lds(
        (const __attribute__((address_space(1))) unsigned int*)gb_,
        (__attribute__((address_space(3))) unsigned int*)&Bs[r_*4096 + wid*1024], 16, 0, 0);
    }
    __syncthreads();   // compiler drains vmcnt before barrier -> tile ready

    // ---- compute: plain C++ reads, compiler-scheduled waits ----
    #pragma unroll
    for (int kk = 0; kk < 2; ++kk){
      i32x4 av[4], bv[4];
      const int chunk = ((kk*4 + lhi) ^ (l15 & 7)) * 16;   // byte offset
      #pragma unroll
      for (int mi = 0; mi < 4; ++mi)
        av[mi] = *(const i32x4*)&As[(wr*64 + mi*16 + l15)*128 + chunk];
      #pragma unroll
      for (int ni = 0; ni < 4; ++ni)
        bv[ni] = *(const i32x4*)&Bs[(wc*64 + ni*16 + l15)*128 + chunk];
      #pragma unroll
      for (int mi = 0; mi < 4; ++mi)
        #pragma unroll
        for (int ni = 0; ni < 4; ++ni)
          acc[mi][ni] = __builtin_amdgcn_mfma_i32_16x16x64_i8(av[mi], bv[ni], acc[mi][ni], 0, 0, 0);
    }
    __syncthreads();   // protect LDS before next stage overwrites
  }

  // ---- fused epilogue: d2 -> dist -> exp -> *W, column-sum ----
  const int rowbase0 = bm * BM + wr * 64;
  f32x4 rs[4];
  #pragma unroll
  for (int mi = 0; mi < 4; ++mi) rs[mi] = (f32x4){0.f, 0.f, 0.f, 0.f};

  f32x4 x2r[4], sxr[4];
  #pragma unroll
  for (int mi = 0; mi < 4; ++mi){
    x2r[mi] = *(const f32x4*)&x2[rowbase0 + mi * 16 + lhi * 4];
    sxr[mi] = *(const f32x4*)&sx[rowbase0 + mi * 16 + lhi * 4];
  }

  #pragma unroll
  for (int ni = 0; ni < 4; ++ni){
    const int col = bn * BN + wc * 64 + ni * 16 + l15;
    const float c2v = c2[col], scv = sc[col], bt = beta[col], wv = W[col];
    #pragma unroll
    for (int mi = 0; mi < 4; ++mi)
      #pragma unroll
      for (int j = 0; j < 4; ++j){
        float dot  = sxr[mi][j] * scv * (float)acc[mi][ni][j];
        float d2   = x2r[mi][j] + c2v - 2.0f * dot;
        float dist = sqrtf(fmaxf(d2, 0.0f));
        rs[mi][j] += wv * __expf(-bt * dist);   // exp(<=0) can't be inf
      }
  }

  // 16-lane shfl reduce (cols within a frag row)
  #pragma unroll
  for (int mi = 0; mi < 4; ++mi)
    #pragma unroll
    for (int j = 0; j < 4; ++j){
      float v = rs[mi][j];
      v += __shfl_xor(v, 1, 16);
      v += __shfl_xor(v, 2, 16);
      v += __shfl_xor(v, 4, 16);
      v += __shfl_xor(v, 8, 16);
      rs[mi][j] = v;
    }

  // cross-wc combine through LDS (As is dead after the last barrier above):
  // wc=1 waves deposit, wc=0 waves add -> one atomicAdd per (row, wr).
  float* red = (float*)As;          // [2 wr][64 rows]
  if (wc == 1 && l15 == 0){
    #pragma unroll
    for (int mi = 0; mi < 4; ++mi)
      #pragma unroll
      for (int j = 0; j < 4; ++j)
        red[wr * 64 + mi * 16 + lhi * 4 + j] = rs[mi][j];
  }
  __syncthreads();
  if (wc == 0 && l15 == 0){
    #pragma unroll
    for (int mi = 0; mi < 4; ++mi)
      #pragma unroll
      for (int j = 0; j < 4; ++j){
        const int r = mi * 16 + lhi * 4 + j;
        atomicAdd(&out[rowbase0 + r], rs[mi][j] + red[wr * 64 + r]);
      }
  }
}

// ---------------- naive f32 fallback (only if ws too small) ----------------
__global__ __launch_bounds__(256) void rbf_naive_kernel(
    const float* __restrict__ x, const float* __restrict__ cen,
    const float* __restrict__ beta, const float* __restrict__ W,
    const float* __restrict__ bias, float* __restrict__ out)
{
  __shared__ float4 xs4[Dsz / 4];
  __shared__ float red[256];
  int b = blockIdx.x;
  for (int i = threadIdx.x; i < Dsz / 4; i += 256)
    xs4[i] = ((const float4*)(x + (size_t)b * Dsz))[i];
  __syncthreads();
  float acc = 0.f;
  for (int j = threadIdx.x; j < Csz; j += 256){
    const float4* c4 = (const float4*)(cen + (size_t)j * Dsz);
    float d2 = 0.f;
    for (int k = 0; k < Dsz / 4; ++k){
      float4 cv = c4[k], xv = xs4[k];
      float a0 = xv.x - cv.x, a1 = xv.y - cv.y, a2 = xv.z - cv.z, a3 = xv.w - cv.w;
      d2 += a0*a0 + a1*a1 + a2*a2 + a3*a3;
    }
    acc += W[j] * expf(-beta[j] * sqrtf(fmaxf(d2, 0.f)));
  }
  red[threadIdx.x] = acc;
  __syncthreads();
  for (int s = 128; s >= 1; s >>= 1){
    if (threadIdx.x < s) red[threadIdx.x] += red[threadIdx.x + s];
    __syncthreads();
  }
  if (threadIdx.x == 0) out[b] = red[0] + bias[0];
}

extern "C" void kernel_launch(void* const* d_in, const int* in_sizes, int n_in,
                              void* d_out, int out_size, void* d_ws, size_t ws_size,
                              hipStream_t stream)
{
  const float* x    = (const float*)d_in[0];
  const float* cen  = (const float*)d_in[1];
  const float* beta = (const float*)d_in[2];
  const float* W    = (const float*)d_in[3];
  const float* bias = (const float*)d_in[4];
  float* out = (float*)d_out;

  const size_t off_xq = 0;
  const size_t off_cq = off_xq + (size_t)Bsz * Dsz;
  const size_t off_x2 = off_cq + (size_t)Csz * Dsz;
  const size_t off_c2 = off_x2 + (size_t)Bsz * sizeof(float);
  const size_t off_sx = off_c2 + (size_t)Csz * sizeof(float);
  const size_t off_sc = off_sx + (size_t)Bsz * sizeof(float);
  const size_t need   = off_sc + (size_t)Csz * sizeof(float);

  if (ws_size < need){
    rbf_naive_kernel<<<Bsz, 256, 0, stream>>>(x, cen, beta, W, bias, out);
    return;
  }

  char* ws = (char*)d_ws;
  signed char* xq = (signed char*)(ws + off_xq);
  signed char* cq = (signed char*)(ws + off_cq);
  float* x2 = (float*)(ws + off_x2);
  float* c2 = (float*)(ws + off_c2);
  float* sx = (float*)(ws + off_sx);
  float* sc = (float*)(ws + off_sc);

  prep_kernel<<<1024, 256, 0, stream>>>(x, cen, bias, xq, cq, x2, c2, sx, sc, out);
  rbf_gemm_kernel<<<1024, 256, 0, stream>>>(xq, cq, x2, c2, sx, sc, beta, W, out);
}